// Round 9
// baseline (150.957 us; speedup 1.0000x reference)
//
#include <hip/hip_runtime.h>
#include <hip/hip_bf16.h>

#define B_ 16
#define S_ 512
#define H_ 768
#define TS_ 20
#define IS_ 20
#define D_ 808
#define M_ 36
#define E_ 12
#define RNUM_ 97
#define D2_ 50
#define P_ (E_*E_)        // 144
#define NODES_ (M_+1)     // 37
#define NCOL_ (D2_*D_)    // 40400
#define MROWS_ (B_*E_)    // 192
#define KSTEPS_ 26
#define KPAD_ (KSTEPS_*32)  // 832
#define BLKPAD_ 1040        // 1024B (4 k-rows x 64 cols fp32) + 16B pad
#define TILEB_ (8*BLKPAD_)  // 8320 B per K-step tile

typedef __attribute__((ext_vector_type(8))) short bf16x8;
typedef __attribute__((ext_vector_type(4))) float f32x4;

__device__ inline unsigned short f2bf(float f) {
  union { float f; unsigned u; } v; v.f = f;
  unsigned r = v.u + 0x7FFFu + ((v.u >> 16) & 1u);
  return (unsigned short)(r >> 16);
}

__device__ inline unsigned pack2bf(float a, float b) {
  union { __hip_bfloat162 h; unsigned u; } p;
  p.h = __float22bfloat162_rn(make_float2(a, b));
  return p.u;
}

__device__ inline void gll16(const float* src, void* lds) {
  __builtin_amdgcn_global_load_lds(
      (const __attribute__((address_space(1))) unsigned int*)src,
      (__attribute__((address_space(3))) unsigned int*)lds, 16, 0, 0);
}

// ---------------- kernel 1: mention mean-pooling (+ cls node) ----------------
// midv row preloaded to LDS: the 512-iteration scan reads LDS broadcasts
// (~6 cyc) instead of loop-carried global loads (~100+ cyc).
__global__ __launch_bounds__(256) void k_mention_pool(
    const float* __restrict__ enc_hid, const int* __restrict__ etype,
    const int* __restrict__ eidv, const int* __restrict__ midv,
    const float* __restrict__ type_emb, const float* __restrict__ id_emb,
    float* __restrict__ x) {
  int blk = blockIdx.x;
  int b = blk / NODES_;
  int n = blk % NODES_;
  int t = threadIdx.x;
  __shared__ int mid[S_];
  for (int s = t; s < S_; s += 256) mid[s] = midv[b * S_ + s];
  __syncthreads();
  float* xrow = x + (size_t)(b * NODES_ + n) * D_;
  if (n == 0) {
    for (int d = t; d < D_; d += 256)
      xrow[d] = (d < H_) ? enc_hid[(size_t)(b * S_) * H_ + d] : 0.0f;
    return;
  }
  float acc[4] = {0.f, 0.f, 0.f, 0.f};
  int cnt = 0;
  for (int s = 0; s < S_; ++s) {
    if (mid[s] != n) continue;
    ++cnt;
    int ty = etype[b * S_ + s];
    int iv = eidv[b * S_ + s];
    #pragma unroll
    for (int ii = 0; ii < 4; ++ii) {
      int d = t + ii * 256;
      if (d < D_) {
        float v;
        if (d < H_) v = enc_hid[(size_t)(b * S_ + s) * H_ + d];
        else if (d < H_ + TS_) v = type_emb[ty * TS_ + (d - H_)];
        else v = id_emb[iv * IS_ + (d - H_ - TS_)];
        acc[ii] += v;
      }
    }
  }
  float inv = (cnt > 0) ? 1.0f / (float)cnt : 0.0f;
  #pragma unroll
  for (int ii = 0; ii < 4; ++ii) {
    int d = t + ii * 256;
    if (d < D_) xrow[d] = acc[ii] * inv;
  }
}

// ---------------- kernel 2: entity pooling -> bf16 pre-swizzled eswz ---------
// eswz bf16 layout [slice=kb*4+g (26*4)][row=192][8], zero-padded k=808..831.
__global__ __launch_bounds__(256) void k_entity_pool(
    const float* __restrict__ x, const float* __restrict__ tbl,
    short* __restrict__ eswz) {
  int blk = blockIdx.x;
  int b = blk / E_;
  int e = blk % E_;
  int t = threadIdx.x;
  const float* trow = tbl + (size_t)(b * (E_ + 1) + (e + 1)) * NODES_;
  __shared__ float w[NODES_];
  __shared__ float sinv;
  if (t < NODES_) w[t] = trow[t];
  __syncthreads();
  if (t == 0) {
    float s = 0.f;
    for (int m = 0; m < NODES_; ++m) s += w[m];
    sinv = (s > 0.f) ? 1.0f / s : 0.0f;
  }
  __syncthreads();
  float inv = sinv;
  for (int d = t; d < D_; d += 256) {
    float a = 0.f;
    for (int m = 0; m < NODES_; ++m)
      a += w[m] * x[(size_t)(b * NODES_ + m) * D_ + d];
    float v = a * inv;
    int slice = d >> 3;
    int el = d & 7;
    eswz[((size_t)slice * MROWS_ + blk) * 8 + el] = (short)f2bf(v);
  }
  if (t < KPAD_ - D_) {   // zero-pad k = 808..831
    int d = D_ + t;
    eswz[((size_t)(d >> 3) * MROWS_ + blk) * 8 + (d & 7)] = 0;
  }
}

// ---------------- kernel 3: Abf[192,40400] = Ent @ Wview (fused, 1 W pass) ---
// BM=192 BN=64 BK=32. W fp32 -> LDS via global_load_lds, padded layout:
// byte(k,c) = (k>>2)*1040 + (k&3)*256 + c*4  (16B pad per 4-row block ->
// bank = (4*(k>>2)+c)%32 -> exactly 2-way = free).
// Waves 2x2: wave owns 96 rows x 32 cols -> B LDS reads = 16KB/step (2x amp).
// A-frags direct bf16 global from eswz (L2-hot). 3-buf, stage 2 ahead.
__global__ __launch_bounds__(256) void k_gemm(
    const float* __restrict__ Wf, const short* __restrict__ eswz,
    short* __restrict__ Abf) {
  __shared__ __align__(16) char Bs[3 * TILEB_];   // 24.96 KiB
  const int tid = threadIdx.x;
  const int lane = tid & 63;
  const int ln15 = lane & 15;
  const int g = (lane >> 4) & 3;
  const int wv = tid >> 6;
  const int wr = wv >> 1;          // 0..1: row half (96 rows)
  const int wc = wv & 1;           // 0..1: col half (32 cols)
  const int colBase = blockIdx.x * 64;

  f32x4 acc[6][2];
  #pragma unroll
  for (int i = 0; i < 6; ++i)
    #pragma unroll
    for (int j = 0; j < 2; ++j)
      acc[i][j] = (f32x4){0.f, 0.f, 0.f, 0.f};

  // stage tile t into buffer bufi: 2 instrs/thread, each = one 4-row block
  auto STAGE = [&](int t, int bufi) {
    #pragma unroll
    for (int r2 = 0; r2 < 2; ++r2) {
      int bi = r2 * 4 + wv;                      // block 0..7 (wave-uniform)
      int kg = t * 32 + bi * 4 + (lane >> 4);    // per-lane k row
      if (kg > D_ - 1) kg = D_ - 1;              // tail: killed by eswz zeros
      int cg = colBase + ln15 * 4;
      if (cg > NCOL_ - 4) cg = NCOL_ - 4;        // last block clamp
      gll16(Wf + (size_t)kg * NCOL_ + cg, Bs + bufi * TILEB_ + bi * BLKPAD_);
    }
  };

  STAGE(0, 0);
  STAGE(1, 1);
  __syncthreads();

  int rb = 0;
  for (int t = 0; t < KSTEPS_; ++t) {
    int sb = rb + 2; if (sb >= 3) sb -= 3;
    if (t + 2 < KSTEPS_) STAGE(t + 2, sb);
    const char* bb = Bs + rb * TILEB_;
    // B fragments: 16 fp32 LDS reads (2-way banks = free), cvt to bf16
    bf16x8 bfr[2];
    #pragma unroll
    for (int nt = 0; nt < 2; ++nt) {
      float f[8];
      #pragma unroll
      for (int e = 0; e < 8; ++e) {
        int k = g * 8 + e;
        int col = wc * 32 + nt * 16 + ln15;
        f[e] = *(const float*)(bb + (k >> 2) * BLKPAD_ + (k & 3) * 256 + col * 4);
      }
      union { bf16x8 v; unsigned u[4]; } u;
      #pragma unroll
      for (int e2 = 0; e2 < 4; ++e2)
        u.u[e2] = pack2bf(f[2 * e2], f[2 * e2 + 1]);
      bfr[nt] = u.v;
    }
    // A fragments: 6 x dwordx4 from eswz (L2-resident)
    bf16x8 af[6];
    #pragma unroll
    for (int mt = 0; mt < 6; ++mt)
      af[mt] = *(const bf16x8*)&eswz[
          ((size_t)(t * 4 + g) * MROWS_ + wr * 96 + mt * 16 + ln15) * 8];
    #pragma unroll
    for (int mt = 0; mt < 6; ++mt)
      #pragma unroll
      for (int nt = 0; nt < 2; ++nt)
        acc[mt][nt] = __builtin_amdgcn_mfma_f32_16x16x32_bf16(
            af[mt], bfr[nt], acc[mt][nt], 0, 0, 0);
    __syncthreads();
    rb = (rb == 2) ? 0 : rb + 1;
  }

  // epilogue: C/D layout col = lane&15, row = g*4 + j; store bf16
  #pragma unroll
  for (int mt = 0; mt < 6; ++mt) {
    int row = wr * 96 + mt * 16 + g * 4;
    #pragma unroll
    for (int nt = 0; nt < 2; ++nt) {
      int col = colBase + wc * 32 + nt * 16 + ln15;
      if (col < NCOL_) {
        #pragma unroll
        for (int j = 0; j < 4; ++j)
          Abf[(size_t)(row + j) * NCOL_ + col] = (short)f2bf(acc[mt][nt][j]);
      }
    }
  }
}

// ---------------- kernel 4a: z via MFMA — one wave per (b, r) ---------------
__global__ __launch_bounds__(64) void k_score_z(
    const short* __restrict__ Abf, const short* __restrict__ eswz,
    float* __restrict__ zbuf) {
  int w = blockIdx.x;            // 0..799
  int b = w / D2_;
  int r = w % D2_;
  int lane = threadIdx.x;
  int ln15 = lane & 15;
  int g = lane >> 4;
  int m = b * E_ + ln15;
  if (m > MROWS_ - 1) m = MROWS_ - 1;
  const short* ab = Abf + (size_t)m * NCOL_ + (size_t)r * D_ + g * 8;
  const short* bb = eswz + ((size_t)g * MROWS_ + m) * 8;
  f32x4 acc = (f32x4){0.f, 0.f, 0.f, 0.f};
  #pragma unroll
  for (int t = 0; t < KSTEPS_; ++t) {
    bf16x8 af = *(const bf16x8*)(ab + t * 32);
    bf16x8 bf = *(const bf16x8*)(bb + (size_t)t * 4 * MROWS_ * 8);
    acc = __builtin_amdgcn_mfma_f32_16x16x32_bf16(af, bf, acc, 0, 0, 0);
  }
  if (ln15 < E_ && g < 3) {
    #pragma unroll
    for (int jj = 0; jj < 4; ++jj)
      zbuf[(size_t)(b * E_ + g * 4 + jj) * (D2_ * E_) + r * E_ + ln15] = acc[jj];
  }
}

// ---------------- kernel 4b: BN + R projection ------------------------------
__global__ __launch_bounds__(256) void k_out(
    const float* __restrict__ zbuf, const float* __restrict__ Rm,
    const float* __restrict__ gam, const float* __restrict__ bet,
    const float* __restrict__ mu, const float* __restrict__ var,
    float* __restrict__ out) {
  int blk = blockIdx.x;   // b*12+ke
  int t = threadIdx.x;
  __shared__ float zS[D2_ * E_];       // 600
  __shared__ float Rs[RNUM_ * D2_];    // 4850
  for (int i = t; i < D2_ * E_; i += 256) {
    int r = i / E_;
    float z = zbuf[(size_t)blk * (D2_ * E_) + i];
    zS[i] = (z - mu[r]) * rsqrtf(var[r] + 1e-5f) * gam[r] + bet[r];
  }
  for (int i = t; i < RNUM_ * D2_; i += 256) Rs[i] = Rm[i];
  __syncthreads();
  for (int o = t; o < E_ * RNUM_; o += 256) {
    int je = o / RNUM_;
    int k = o % RNUM_;
    float s = 0.f;
    #pragma unroll
    for (int r = 0; r < D2_; ++r) s += zS[r * E_ + je] * Rs[k * D2_ + r];
    out[(size_t)blk * (E_ * RNUM_) + o] = s;
  }
}

extern "C" void kernel_launch(void* const* d_in, const int* in_sizes, int n_in,
                              void* d_out, int out_size, void* d_ws, size_t ws_size,
                              hipStream_t stream) {
  const float* enc  = (const float*)d_in[0];
  const int*  etype = (const int*)d_in[1];
  const int*  eidv  = (const int*)d_in[2];
  const int*  midv  = (const int*)d_in[3];
  const float* tbl  = (const float*)d_in[4];
  const float* temb = (const float*)d_in[5];
  const float* iemb = (const float*)d_in[6];
  const float* W    = (const float*)d_in[7];
  const float* Rm   = (const float*)d_in[8];
  const float* gam  = (const float*)d_in[9];
  const float* bet  = (const float*)d_in[10];
  const float* mu   = (const float*)d_in[11];
  const float* var  = (const float*)d_in[12];

  // ws layout: zbuf | eswz | Abf | x
  float* ws   = (float*)d_ws;
  float* zbuf = ws;                                           // 115,200 f
  short* eswz = (short*)(zbuf + (size_t)MROWS_ * D2_ * E_);   // 159,744 sh
  short* Abf  = eswz + (size_t)104 * MROWS_ * 8;              // 7,756,800 sh
  float* x    = (float*)(Abf + (size_t)MROWS_ * NCOL_);       // 478,336 f
  float* out  = (float*)d_out;

  hipLaunchKernelGGL(k_mention_pool, dim3(B_ * NODES_), dim3(256), 0, stream,
                     enc, etype, eidv, midv, temb, iemb, x);
  hipLaunchKernelGGL(k_entity_pool, dim3(MROWS_), dim3(256), 0, stream,
                     x, tbl, eswz);
  hipLaunchKernelGGL(k_gemm, dim3((NCOL_ + 63) / 64), dim3(256), 0, stream,
                     W, eswz, Abf);
  hipLaunchKernelGGL(k_score_z, dim3(B_ * D2_), dim3(64), 0, stream,
                     Abf, eswz, zbuf);
  hipLaunchKernelGGL(k_out, dim3(MROWS_), dim3(256), 0, stream,
                     zbuf, Rm, gam, bet, mu, var, out);
}

// Round 10
// 104.008 us; speedup vs baseline: 1.4514x; 1.4514x over previous
//
#include <hip/hip_runtime.h>
#include <hip/hip_bf16.h>

#define B_ 16
#define S_ 512
#define H_ 768
#define TS_ 20
#define IS_ 20
#define D_ 808
#define M_ 36
#define E_ 12
#define RNUM_ 97
#define D2_ 50
#define P_ (E_*E_)        // 144
#define NODES_ (M_+1)     // 37
#define NCOL_ (D2_*D_)    // 40400
#define MROWS_ (B_*E_)    // 192
#define KSTEPS_ 26
#define KPAD_ (KSTEPS_*32)  // 832
#define BLKPAD_ 1040        // 1024B (4 k-rows x 64 cols fp32) + 16B pad
#define TILEB_ (8*BLKPAD_)  // 8320 B per K-step tile

typedef __attribute__((ext_vector_type(8))) short bf16x8;
typedef __attribute__((ext_vector_type(4))) float f32x4;

__device__ inline unsigned short f2bf(float f) {
  union { float f; unsigned u; } v; v.f = f;
  unsigned r = v.u + 0x7FFFu + ((v.u >> 16) & 1u);
  return (unsigned short)(r >> 16);
}

__device__ inline unsigned pack2bf(float a, float b) {
  union { __hip_bfloat162 h; unsigned u; } p;
  p.h = __float22bfloat162_rn(make_float2(a, b));
  return p.u;
}

__device__ inline void gll16(const float* src, void* lds) {
  __builtin_amdgcn_global_load_lds(
      (const __attribute__((address_space(1))) unsigned int*)src,
      (__attribute__((address_space(3))) unsigned int*)lds, 16, 0, 0);
}

// ---------------- kernel 1: mention mean-pooling (+ cls node) ----------------
// Ballot-compaction of matched tokens (ordered, deterministic), then a
// branch-free accumulation loop with static per-thread dims:
//   t -> d = t, t+256, t+512 (enc);  t < 40 -> emb dims 768..807.
__global__ __launch_bounds__(256) void k_mention_pool(
    const float* __restrict__ enc_hid, const int* __restrict__ etype,
    const int* __restrict__ eidv, const int* __restrict__ midv,
    const float* __restrict__ type_emb, const float* __restrict__ id_emb,
    float* __restrict__ x) {
  int blk = blockIdx.x;
  int b = blk / NODES_;
  int n = blk % NODES_;
  int t = threadIdx.x;
  float* xrow = x + (size_t)(b * NODES_ + n) * D_;
  if (n == 0) {
    for (int d = t; d < D_; d += 256)
      xrow[d] = (d < H_) ? enc_hid[(size_t)(b * S_) * H_ + d] : 0.0f;
    return;
  }
  __shared__ int midS[S_], tyS[S_], ivS[S_], list[S_];
  __shared__ int cntS;
  for (int s = t; s < S_; s += 256) {
    midS[s] = midv[b * S_ + s];
    tyS[s]  = etype[b * S_ + s];
    ivS[s]  = eidv[b * S_ + s];
  }
  __syncthreads();
  if (t < 64) {   // wave 0: ordered compaction via ballot
    int base = 0;
    #pragma unroll
    for (int c = 0; c < 8; ++c) {
      int s = c * 64 + t;
      bool m = (midS[s] == n);
      unsigned long long bal = __ballot(m);
      int pos = base + __popcll(bal & ((1ULL << t) - 1ULL));
      if (m) list[pos] = s;
      base += __popcll(bal);
    }
    if (t == 0) cntS = base;
  }
  __syncthreads();
  int cnt = cntS;
  float a0 = 0.f, a1 = 0.f, a2 = 0.f, a3 = 0.f;
  for (int i = 0; i < cnt; ++i) {
    int s = list[i];
    const float* er = enc_hid + (size_t)(b * S_ + s) * H_;
    a0 += er[t];
    a1 += er[t + 256];
    a2 += er[t + 512];
    if (t < TS_ + IS_) {
      int ty = tyS[s], iv = ivS[s];
      a3 += (t < TS_) ? type_emb[ty * TS_ + t] : id_emb[iv * IS_ + (t - TS_)];
    }
  }
  float inv = (cnt > 0) ? 1.0f / (float)cnt : 0.0f;
  xrow[t] = a0 * inv;
  xrow[t + 256] = a1 * inv;
  xrow[t + 512] = a2 * inv;
  if (t < TS_ + IS_) xrow[H_ + t] = a3 * inv;
}

// ---------------- kernel 2: entity pooling -> bf16 pre-swizzled eswz ---------
// eswz bf16 layout [slice=kb*4+g (26*4)][row=192][8], zero-padded k=808..831.
__global__ __launch_bounds__(256) void k_entity_pool(
    const float* __restrict__ x, const float* __restrict__ tbl,
    short* __restrict__ eswz) {
  int blk = blockIdx.x;
  int b = blk / E_;
  int e = blk % E_;
  int t = threadIdx.x;
  const float* trow = tbl + (size_t)(b * (E_ + 1) + (e + 1)) * NODES_;
  __shared__ float w[NODES_];
  __shared__ float sinv;
  if (t < NODES_) w[t] = trow[t];
  __syncthreads();
  if (t == 0) {
    float s = 0.f;
    for (int m = 0; m < NODES_; ++m) s += w[m];
    sinv = (s > 0.f) ? 1.0f / s : 0.0f;
  }
  __syncthreads();
  float inv = sinv;
  for (int d = t; d < D_; d += 256) {
    float a = 0.f;
    for (int m = 0; m < NODES_; ++m)
      a += w[m] * x[(size_t)(b * NODES_ + m) * D_ + d];
    float v = a * inv;
    int slice = d >> 3;
    int el = d & 7;
    eswz[((size_t)slice * MROWS_ + blk) * 8 + el] = (short)f2bf(v);
  }
  if (t < KPAD_ - D_) {   // zero-pad k = 808..831
    int d = D_ + t;
    eswz[((size_t)(d >> 3) * MROWS_ + blk) * 8 + (d & 7)] = 0;
  }
}

// ---------------- kernel 3: Abf[192,40400] = Ent @ Wview (fused, 1 W pass) ---
// BM=192 BN=64 BK=32. W fp32 -> LDS via global_load_lds, padded layout:
// byte(k,c) = (k>>2)*1040 + (k&3)*256 + c*4  (2-way banks = free).
// Waves 2x2. A-frags direct bf16 global from eswz (L2-hot). 3-buf.
__global__ __launch_bounds__(256) void k_gemm(
    const float* __restrict__ Wf, const short* __restrict__ eswz,
    short* __restrict__ Abf) {
  __shared__ __align__(16) char Bs[3 * TILEB_];   // 24.96 KiB
  const int tid = threadIdx.x;
  const int lane = tid & 63;
  const int ln15 = lane & 15;
  const int g = (lane >> 4) & 3;
  const int wv = tid >> 6;
  const int wr = wv >> 1;          // 0..1: row half (96 rows)
  const int wc = wv & 1;           // 0..1: col half (32 cols)
  const int colBase = blockIdx.x * 64;

  f32x4 acc[6][2];
  #pragma unroll
  for (int i = 0; i < 6; ++i)
    #pragma unroll
    for (int j = 0; j < 2; ++j)
      acc[i][j] = (f32x4){0.f, 0.f, 0.f, 0.f};

  auto STAGE = [&](int t, int bufi) {
    #pragma unroll
    for (int r2 = 0; r2 < 2; ++r2) {
      int bi = r2 * 4 + wv;
      int kg = t * 32 + bi * 4 + (lane >> 4);
      if (kg > D_ - 1) kg = D_ - 1;
      int cg = colBase + ln15 * 4;
      if (cg > NCOL_ - 4) cg = NCOL_ - 4;
      gll16(Wf + (size_t)kg * NCOL_ + cg, Bs + bufi * TILEB_ + bi * BLKPAD_);
    }
  };

  STAGE(0, 0);
  STAGE(1, 1);
  __syncthreads();

  int rb = 0;
  for (int t = 0; t < KSTEPS_; ++t) {
    int sb = rb + 2; if (sb >= 3) sb -= 3;
    if (t + 2 < KSTEPS_) STAGE(t + 2, sb);
    const char* bb = Bs + rb * TILEB_;
    bf16x8 bfr[2];
    #pragma unroll
    for (int nt = 0; nt < 2; ++nt) {
      float f[8];
      #pragma unroll
      for (int e = 0; e < 8; ++e) {
        int k = g * 8 + e;
        int col = wc * 32 + nt * 16 + ln15;
        f[e] = *(const float*)(bb + (k >> 2) * BLKPAD_ + (k & 3) * 256 + col * 4);
      }
      union { bf16x8 v; unsigned u[4]; } u;
      #pragma unroll
      for (int e2 = 0; e2 < 4; ++e2)
        u.u[e2] = pack2bf(f[2 * e2], f[2 * e2 + 1]);
      bfr[nt] = u.v;
    }
    bf16x8 af[6];
    #pragma unroll
    for (int mt = 0; mt < 6; ++mt)
      af[mt] = *(const bf16x8*)&eswz[
          ((size_t)(t * 4 + g) * MROWS_ + wr * 96 + mt * 16 + ln15) * 8];
    #pragma unroll
    for (int mt = 0; mt < 6; ++mt)
      #pragma unroll
      for (int nt = 0; nt < 2; ++nt)
        acc[mt][nt] = __builtin_amdgcn_mfma_f32_16x16x32_bf16(
            af[mt], bfr[nt], acc[mt][nt], 0, 0, 0);
    __syncthreads();
    rb = (rb == 2) ? 0 : rb + 1;
  }

  #pragma unroll
  for (int mt = 0; mt < 6; ++mt) {
    int row = wr * 96 + mt * 16 + g * 4;
    #pragma unroll
    for (int nt = 0; nt < 2; ++nt) {
      int col = colBase + wc * 32 + nt * 16 + ln15;
      if (col < NCOL_) {
        #pragma unroll
        for (int j = 0; j < 4; ++j)
          Abf[(size_t)(row + j) * NCOL_ + col] = (short)f2bf(acc[mt][nt][j]);
      }
    }
  }
}

// ---------------- kernel 4a: z via MFMA — one wave per (b, r) ---------------
__global__ __launch_bounds__(64) void k_score_z(
    const short* __restrict__ Abf, const short* __restrict__ eswz,
    float* __restrict__ zbuf) {
  int w = blockIdx.x;            // 0..799
  int b = w / D2_;
  int r = w % D2_;
  int lane = threadIdx.x;
  int ln15 = lane & 15;
  int g = lane >> 4;
  int m = b * E_ + ln15;
  if (m > MROWS_ - 1) m = MROWS_ - 1;
  const short* ab = Abf + (size_t)m * NCOL_ + (size_t)r * D_ + g * 8;
  const short* bb = eswz + ((size_t)g * MROWS_ + m) * 8;
  f32x4 acc = (f32x4){0.f, 0.f, 0.f, 0.f};
  #pragma unroll
  for (int t = 0; t < KSTEPS_; ++t) {
    bf16x8 af = *(const bf16x8*)(ab + t * 32);
    bf16x8 bf = *(const bf16x8*)(bb + (size_t)t * 4 * MROWS_ * 8);
    acc = __builtin_amdgcn_mfma_f32_16x16x32_bf16(af, bf, acc, 0, 0, 0);
  }
  if (ln15 < E_ && g < 3) {
    #pragma unroll
    for (int jj = 0; jj < 4; ++jj)
      zbuf[(size_t)(b * E_ + g * 4 + jj) * (D2_ * E_) + r * E_ + ln15] = acc[jj];
  }
}

// ---------------- kernel 4b: BN + R projection ------------------------------
__global__ __launch_bounds__(256) void k_out(
    const float* __restrict__ zbuf, const float* __restrict__ Rm,
    const float* __restrict__ gam, const float* __restrict__ bet,
    const float* __restrict__ mu, const float* __restrict__ var,
    float* __restrict__ out) {
  int blk = blockIdx.x;   // b*12+ke
  int t = threadIdx.x;
  __shared__ float zS[D2_ * E_];       // 600
  __shared__ float Rs[RNUM_ * D2_];    // 4850
  for (int i = t; i < D2_ * E_; i += 256) {
    int r = i / E_;
    float z = zbuf[(size_t)blk * (D2_ * E_) + i];
    zS[i] = (z - mu[r]) * rsqrtf(var[r] + 1e-5f) * gam[r] + bet[r];
  }
  for (int i = t; i < RNUM_ * D2_; i += 256) Rs[i] = Rm[i];
  __syncthreads();
  for (int o = t; o < E_ * RNUM_; o += 256) {
    int je = o / RNUM_;
    int k = o % RNUM_;
    float s = 0.f;
    #pragma unroll
    for (int r = 0; r < D2_; ++r) s += zS[r * E_ + je] * Rs[k * D2_ + r];
    out[(size_t)blk * (E_ * RNUM_) + o] = s;
  }
}

extern "C" void kernel_launch(void* const* d_in, const int* in_sizes, int n_in,
                              void* d_out, int out_size, void* d_ws, size_t ws_size,
                              hipStream_t stream) {
  const float* enc  = (const float*)d_in[0];
  const int*  etype = (const int*)d_in[1];
  const int*  eidv  = (const int*)d_in[2];
  const int*  midv  = (const int*)d_in[3];
  const float* tbl  = (const float*)d_in[4];
  const float* temb = (const float*)d_in[5];
  const float* iemb = (const float*)d_in[6];
  const float* W    = (const float*)d_in[7];
  const float* Rm   = (const float*)d_in[8];
  const float* gam  = (const float*)d_in[9];
  const float* bet  = (const float*)d_in[10];
  const float* mu   = (const float*)d_in[11];
  const float* var  = (const float*)d_in[12];

  // ws layout: zbuf | eswz | Abf | x
  float* ws   = (float*)d_ws;
  float* zbuf = ws;                                           // 115,200 f
  short* eswz = (short*)(zbuf + (size_t)MROWS_ * D2_ * E_);   // 159,744 sh
  short* Abf  = eswz + (size_t)104 * MROWS_ * 8;              // 7,756,800 sh
  float* x    = (float*)(Abf + (size_t)MROWS_ * NCOL_);       // 478,336 f
  float* out  = (float*)d_out;

  hipLaunchKernelGGL(k_mention_pool, dim3(B_ * NODES_), dim3(256), 0, stream,
                     enc, etype, eidv, midv, temb, iemb, x);
  hipLaunchKernelGGL(k_entity_pool, dim3(MROWS_), dim3(256), 0, stream,
                     x, tbl, eswz);
  hipLaunchKernelGGL(k_gemm, dim3((NCOL_ + 63) / 64), dim3(256), 0, stream,
                     W, eswz, Abf);
  hipLaunchKernelGGL(k_score_z, dim3(B_ * D2_), dim3(64), 0, stream,
                     Abf, eswz, zbuf);
  hipLaunchKernelGGL(k_out, dim3(MROWS_), dim3(256), 0, stream,
                     zbuf, Rm, gam, bet, mu, var, out);
}